// Round 11
// baseline (276.880 us; speedup 1.0000x reference)
//
#include <hip/hip_runtime.h>
#include <hip/hip_bf16.h>
#include <cstddef>

// 3-layer tanh RNN (B=8192, T=80, D=32, H=64), fused, MFMA, REGISTER-ONLY (R9)
// + INTRA-WAVE LAYER SKEW, FULLY PEELED (no guards, no conditional liveness).
//
// D==B IDENTITY (K=16 MFMA): B-frag map B[k=4*(lane>>4)+i][n=lane&15] equals the
// C/D map D[row=4*(lane>>4)+r][col=lane&15], so a tanh'd packed D-tile IS the
// next GEMM's B-operand (k=j, n=batch). No LDS, no barriers, no shuffles.
// (Verified end-to-end by R9: passed, absmax 0.015625.)
//
// SKEW: at iteration tau the wave computes h0(tau), h1(tau-1), h2(tau-2) from
// PREVIOUS-iteration registers h0(tau-1), h1(tau-2), h2(tau-3). All 84 MFMAs
// of an iteration are independent of all 12 tanh_packs of the same iteration:
// program order [MFMA L0 L1 L2][tanh L0 L1 L2] -> matrix pipe overlaps the
// VALU/trans burst. R10's guarded version of this FAILED via poison/UB
// (conditionally-uninitialized accumulator arrays let the compiler collapse
// the guards); this version peels prologue (tau=0,1) and epilogue (tau=80,81)
// explicitly so every value read is unconditionally defined.
//
// One wave owns 16 batches end-to-end; 512 independent waves (B/16), no sync.
// Weights VGPR-resident (A-frags); h state = 4 s16x4 B-frags/layer in regs.

typedef __attribute__((ext_vector_type(8))) short s16x8;
typedef __attribute__((ext_vector_type(4))) short s16x4;
typedef __attribute__((ext_vector_type(4))) float fx4;

#define MFMA32(A, B, C) __builtin_amdgcn_mfma_f32_16x16x32_bf16((A), (B), (C), 0, 0, 0)
#define MFMA16(A, B, C) __builtin_amdgcn_mfma_f32_16x16x16bf16_1k((A), (B), (C), 0, 0, 0)

#if __has_builtin(__builtin_amdgcn_exp2f)
#define EXP2F(x) __builtin_amdgcn_exp2f(x)
#else
#define EXP2F(x) exp2f(x)
#endif
#if __has_builtin(__builtin_amdgcn_rcpf)
#define RCPF(x) __builtin_amdgcn_rcpf(x)
#else
#define RCPF(x) (1.0f / (x))
#endif

static constexpr float K2LOG2E = 2.8853900817779268f;  // 2*log2(e)

__device__ __forceinline__ short f2bf(float f) {  // RNE float->bf16 (weights, one-time)
  union { float f; unsigned u; } v; v.f = f;
  unsigned r = v.u + 0x7FFFu + ((v.u >> 16) & 1u);
  return (short)(r >> 16);
}
__device__ __forceinline__ float bf2f(short s) {
  union { unsigned u; float f; } v; v.u = ((unsigned)(unsigned short)s) << 16;
  return v.f;
}
__device__ __forceinline__ unsigned pk2bf(float a, float b) {  // v_cvt_pk_bf16_f32
  float2 t; t.x = a; t.y = b;
  union { __hip_bfloat162 h; unsigned u; } c;
  c.h = __float22bfloat162_rn(t);
  return c.u;
}

__device__ __forceinline__ s16x4 wfragA16(const float* W, int ncols, int row, int col0) {
  const float* p = W + row * ncols + col0;
  s16x4 r;
#pragma unroll
  for (int i = 0; i < 4; ++i) r[i] = f2bf(p[i]);
  return r;
}
__device__ __forceinline__ s16x8 wfragA32(const float* W, int ncols, int row, int col0) {
  const float* p = W + row * ncols + col0;
  s16x8 r;
#pragma unroll
  for (int i = 0; i < 8; ++i) r[i] = f2bf(p[i]);
  return r;
}

// tanh(acc + bias) (bias pre-scaled by 2*log2e) -> packed bf16 B-frag piece.
__device__ __forceinline__ s16x4 tanh_pack(fx4 acc, const float* bs) {
  float h[4];
#pragma unroll
  for (int r = 0; r < 4; ++r) {
    float e = EXP2F(__builtin_fmaf(acc[r], K2LOG2E, bs[r]));
    h[r] = __builtin_fmaf(-2.f, RCPF(e + 1.f), 1.f);
  }
  union { unsigned u[2]; s16x4 v; } p;
  p.u[0] = pk2bf(h[0], h[1]);
  p.u[1] = pk2bf(h[2], h[3]);
  return p.v;
}

__global__ __launch_bounds__(64, 1) void rnn3_k16p(
    const float* __restrict__ x,
    const float* __restrict__ Wih0, const float* __restrict__ Whh0,
    const float* __restrict__ bih0, const float* __restrict__ bhh0,
    const float* __restrict__ Wih1, const float* __restrict__ Whh1,
    const float* __restrict__ bih1, const float* __restrict__ bhh1,
    const float* __restrict__ Wih2, const float* __restrict__ Whh2,
    const float* __restrict__ bih2, const float* __restrict__ bhh2,
    const float* __restrict__ Wfc, const float* __restrict__ bfc,
    float* __restrict__ out)
{
  const int ln  = threadIdx.x & 63;
  const int Q   = ln >> 4;        // k-group / row-quad
  const int m15 = ln & 15;        // A: row m   |  B/D: col n (batch)
  const int bbase = (int)blockIdx.x * 16;

  // ---------------- weights, VGPR-resident ----------------
  s16x8 wx[4];
#pragma unroll
  for (int t4 = 0; t4 < 4; ++t4) wx[t4] = wfragA32(Wih0, 32, 16 * t4 + m15, 8 * Q);
  s16x4 wh0[4][4], wi1[4][4], wh1[4][4], wi2[4][4], wh2[4][4];
#pragma unroll
  for (int t4 = 0; t4 < 4; ++t4) {
    const int row = 16 * t4 + m15;
#pragma unroll
    for (int kf = 0; kf < 4; ++kf) {
      const int c = 16 * kf + 4 * Q;
      wh0[t4][kf] = wfragA16(Whh0, 64, row, c);
      wi1[t4][kf] = wfragA16(Wih1, 64, row, c);
      wh1[t4][kf] = wfragA16(Whh1, 64, row, c);
      wi2[t4][kf] = wfragA16(Wih2, 64, row, c);
      wh2[t4][kf] = wfragA16(Whh2, 64, row, c);
    }
  }

  // ---------------- biases pre-scaled; lane's j = 16*tile + 4*Q + r ----------
  float bs0[4][4], bs1[4][4], bs2[4][4];
#pragma unroll
  for (int t4 = 0; t4 < 4; ++t4)
#pragma unroll
    for (int r = 0; r < 4; ++r) {
      const int j = 16 * t4 + 4 * Q + r;
      bs0[t4][r] = (bih0[j] + bhh0[j]) * K2LOG2E;
      bs1[t4][r] = (bih1[j] + bhh1[j]) * K2LOG2E;
      bs2[t4][r] = (bih2[j] + bhh2[j]) * K2LOG2E;
    }

  // ---------------- state (all unconditionally defined) ----------------
  const s16x4 z2 = {0, 0, 0, 0};
  s16x4 h0f[4] = {z2, z2, z2, z2};
  s16x4 h1f[4] = {z2, z2, z2, z2};
  s16x4 h2f[4] = {z2, z2, z2, z2};
  const fx4 z4 = {0.f, 0.f, 0.f, 0.f};
  fx4 a0[4] = {z4, z4, z4, z4};
  fx4 a1[4] = {z4, z4, z4, z4};
  fx4 a2[4] = {z4, z4, z4, z4};
  s16x8 xpv = {0, 0, 0, 0, 0, 0, 0, 0};

  // x source: lane reads x[bbase+m15][t][8Q .. 8Q+7] (K=32 B-frag layout)
  const float* xr = x + (size_t)(bbase + m15) * (80 * 32) + 8 * Q;
  fx4 xc0 = *(const fx4*)(xr);
  fx4 xc1 = *(const fx4*)(xr + 4);

  // ---------------- per-stage building blocks (identical at every site) ------
  auto packx = [&](int tcur) {
    union { unsigned u[4]; s16x8 v; } xp;
    xp.u[0] = pk2bf(xc0[0], xc0[1]); xp.u[1] = pk2bf(xc0[2], xc0[3]);
    xp.u[2] = pk2bf(xc1[0], xc1[1]); xp.u[3] = pk2bf(xc1[2], xc1[3]);
    xpv = xp.v;
    const int tn = (tcur < 79) ? tcur + 1 : 79;   // prefetch x(t+1)
    xc0 = *(const fx4*)(xr + tn * 32);
    xc1 = *(const fx4*)(xr + tn * 32 + 4);
  };
  auto mfmaL0 = [&]() {   // a0 = Wih0*x + Whh0*h0f
#pragma unroll
    for (int t4 = 0; t4 < 4; ++t4) a0[t4] = MFMA32(wx[t4], xpv, z4);
#pragma unroll
    for (int kf = 0; kf < 4; ++kf)
#pragma unroll
      for (int t4 = 0; t4 < 4; ++t4) a0[t4] = MFMA16(wh0[t4][kf], h0f[kf], a0[t4]);
  };
  auto mfmaL1 = [&]() {   // a1 = Wih1*h0f + Whh1*h1f
#pragma unroll
    for (int t4 = 0; t4 < 4; ++t4) a1[t4] = MFMA16(wi1[t4][0], h0f[0], z4);
#pragma unroll
    for (int kf = 1; kf < 4; ++kf)
#pragma unroll
      for (int t4 = 0; t4 < 4; ++t4) a1[t4] = MFMA16(wi1[t4][kf], h0f[kf], a1[t4]);
#pragma unroll
    for (int kf = 0; kf < 4; ++kf)
#pragma unroll
      for (int t4 = 0; t4 < 4; ++t4) a1[t4] = MFMA16(wh1[t4][kf], h1f[kf], a1[t4]);
  };
  auto mfmaL2 = [&]() {   // a2 = Wih2*h1f + Whh2*h2f
#pragma unroll
    for (int t4 = 0; t4 < 4; ++t4) a2[t4] = MFMA16(wi2[t4][0], h1f[0], z4);
#pragma unroll
    for (int kf = 1; kf < 4; ++kf)
#pragma unroll
      for (int t4 = 0; t4 < 4; ++t4) a2[t4] = MFMA16(wi2[t4][kf], h1f[kf], a2[t4]);
#pragma unroll
    for (int kf = 0; kf < 4; ++kf)
#pragma unroll
      for (int t4 = 0; t4 < 4; ++t4) a2[t4] = MFMA16(wh2[t4][kf], h2f[kf], a2[t4]);
  };
  auto tanhL0 = [&]() {
#pragma unroll
    for (int t4 = 0; t4 < 4; ++t4) h0f[t4] = tanh_pack(a0[t4], bs0[t4]);
  };
  auto tanhL1 = [&]() {
#pragma unroll
    for (int t4 = 0; t4 < 4; ++t4) h1f[t4] = tanh_pack(a1[t4], bs1[t4]);
  };
  auto tanhL2 = [&]() {
#pragma unroll
    for (int t4 = 0; t4 < 4; ++t4) h2f[t4] = tanh_pack(a2[t4], bs2[t4]);
  };

  // ---------------- prologue ----------------
  // tau=0: h0(0)
  packx(0); mfmaL0(); tanhL0();
  // tau=1: h0(1), h1(0)   (mfmaL1 reads OLD h0f = h0(0) before tanhL0 updates)
  packx(1); mfmaL0(); mfmaL1(); tanhL0(); tanhL1();

  // ---------------- steady state: tau = 2..79 ----------------
  // entering tau: h0f=h0(tau-1), h1f=h1(tau-2), h2f=h2(tau-3)
  for (int tau = 2; tau <= 79; ++tau) {
    packx(tau);
    mfmaL0(); mfmaL1(); mfmaL2();   // all read previous-iteration state only
    tanhL0(); tanhL1(); tanhL2();   // h0(tau), h1(tau-1), h2(tau-2)
  }
  // after loop: h0f=h0(79), h1f=h1(78), h2f=h2(77)

  // ---------------- epilogue ----------------
  // tau=80: h1(79), h2(78)
  mfmaL1(); mfmaL2(); tanhL1(); tanhL2();
  // tau=81: h2(79)
  mfmaL2(); tanhL2();

  // ---------------- FC head: out[b] = Wfc . h2(79) + bfc ----------------
  float sv = 0.f;
#pragma unroll
  for (int kf = 0; kf < 4; ++kf)
#pragma unroll
    for (int i = 0; i < 4; ++i)
      sv += bf2f(h2f[kf][i]) * Wfc[16 * kf + 4 * Q + i];
  sv += __shfl_xor(sv, 16, 64);
  sv += __shfl_xor(sv, 32, 64);
  if (ln < 16) out[bbase + ln] = sv + bfc[0];
}

extern "C" void kernel_launch(void* const* d_in, const int* in_sizes, int n_in,
                              void* d_out, int out_size, void* d_ws, size_t ws_size,
                              hipStream_t stream) {
  const float* x    = (const float*)d_in[0];
  const float* Wih0 = (const float*)d_in[1];
  const float* Whh0 = (const float*)d_in[2];
  const float* bih0 = (const float*)d_in[3];
  const float* bhh0 = (const float*)d_in[4];
  const float* Wih1 = (const float*)d_in[5];
  const float* Whh1 = (const float*)d_in[6];
  const float* bih1 = (const float*)d_in[7];
  const float* bhh1 = (const float*)d_in[8];
  const float* Wih2 = (const float*)d_in[9];
  const float* Whh2 = (const float*)d_in[10];
  const float* bih2 = (const float*)d_in[11];
  const float* bhh2 = (const float*)d_in[12];
  const float* Wfc  = (const float*)d_in[13];
  const float* bfc  = (const float*)d_in[14];

  // 512 blocks x 64 thr = 512 fully independent waves (16 batch rows each).
  rnn3_k16p<<<dim3(512), dim3(64), 0, stream>>>(
      x, Wih0, Whh0, bih0, bhh0, Wih1, Whh1, bih1, bhh1,
      Wih2, Whh2, bih2, bhh2, Wfc, bfc, (float*)d_out);
}

// Round 12
// 192.221 us; speedup vs baseline: 1.4404x; 1.4404x over previous
//
#include <hip/hip_runtime.h>
#include <hip/hip_bf16.h>
#include <cstddef>

// 3-layer tanh RNN (B=8192, T=80, D=32, H=64), fused, MFMA.
// SYSTOLIC LAYER PIPELINE with 4-STEP CHUNKS + register-carried own recurrence.
//
// Block = 192 thr = 3 waves; wave wv = layer wv. Interval m (0..21): wave wv
// computes its layer for t = 4*(m-wv) .. 4*(m-wv)+3 (when in [0,79]).
// ONE barrier per interval (22 total vs R4's 82 per-tick barriers):
//   - upstream inputs for all 4 steps were written last interval -> batched
//     ds_read_b128 at interval top (latency amortized 4x);
//   - own recurrence stays in REGISTERS via the K=16 D==B identity (R9/R11
//     verified): tanh'd packed D-tile IS the next B-operand, no LDS round-trip;
//   - LDS ring hb[layer][t&7][batch][j]: writer slots {4k..4k+3}, downstream
//     reader slots {4k-4..4k-1}, upstream writer {4k+4..4k+7} - disjoint mod 8;
//   - x refilled one interval ahead (vmcnt drain at barrier ~free).
//
// MFMA maps (all verified R2-R11):
//   K=32 A: A[m=lane&15][k=8q+i]; B: B[k=8q+i][n=lane&15]  (q=lane>>4)
//   K=16 A: A[m=lane&15][k=4q+i]; B==D: D[row=4q+r][col=lane&15]
// tanh via exp2 (bias pre-scaled by 2*log2e) - numerics identical to R2-R11.

typedef __attribute__((ext_vector_type(8))) short s16x8;
typedef __attribute__((ext_vector_type(4))) short s16x4;
typedef __attribute__((ext_vector_type(4))) float fx4;

#define MFMA32(A, B, C) __builtin_amdgcn_mfma_f32_16x16x32_bf16((A), (B), (C), 0, 0, 0)
#define MFMA16(A, B, C) __builtin_amdgcn_mfma_f32_16x16x16bf16_1k((A), (B), (C), 0, 0, 0)

#if __has_builtin(__builtin_amdgcn_exp2f)
#define EXP2F(x) __builtin_amdgcn_exp2f(x)
#else
#define EXP2F(x) exp2f(x)
#endif
#if __has_builtin(__builtin_amdgcn_rcpf)
#define RCPF(x) __builtin_amdgcn_rcpf(x)
#else
#define RCPF(x) (1.0f / (x))
#endif

static constexpr float K2LOG2E = 2.8853900817779268f;  // 2*log2(e)

__device__ __forceinline__ short f2bf(float f) {  // RNE float->bf16 (weights, one-time)
  union { float f; unsigned u; } v; v.f = f;
  unsigned r = v.u + 0x7FFFu + ((v.u >> 16) & 1u);
  return (short)(r >> 16);
}
__device__ __forceinline__ float bf2f(short s) {
  union { unsigned u; float f; } v; v.u = ((unsigned)(unsigned short)s) << 16;
  return v.f;
}
__device__ __forceinline__ unsigned pk2bf(float a, float b) {  // v_cvt_pk_bf16_f32
  float2 t; t.x = a; t.y = b;
  union { __hip_bfloat162 h; unsigned u; } c;
  c.h = __float22bfloat162_rn(t);
  return c.u;
}

__device__ __forceinline__ s16x4 wfragA16(const float* W, int ncols, int row, int col0) {
  const float* p = W + row * ncols + col0;
  s16x4 r;
#pragma unroll
  for (int i = 0; i < 4; ++i) r[i] = f2bf(p[i]);
  return r;
}
__device__ __forceinline__ s16x8 wfragA32(const float* W, int ncols, int row, int col0) {
  const float* p = W + row * ncols + col0;
  s16x8 r;
#pragma unroll
  for (int i = 0; i < 8; ++i) r[i] = f2bf(p[i]);
  return r;
}

// tanh(acc + bias) (bias pre-scaled by 2*log2e) -> packed bf16 (K=16 B-frag piece).
__device__ __forceinline__ s16x4 tanh_pack(fx4 acc, const float* bs) {
  float h[4];
#pragma unroll
  for (int r = 0; r < 4; ++r) {
    float e = EXP2F(__builtin_fmaf(acc[r], K2LOG2E, bs[r]));
    h[r] = __builtin_fmaf(-2.f, RCPF(e + 1.f), 1.f);
  }
  union { unsigned u[2]; s16x4 v; } p;
  p.u[0] = pk2bf(h[0], h[1]);
  p.u[1] = pk2bf(h[2], h[3]);
  return p.v;
}

__global__ __launch_bounds__(192, 2) void rnn3_chunk4(
    const float* __restrict__ x,
    const float* __restrict__ Wih0, const float* __restrict__ Whh0,
    const float* __restrict__ bih0, const float* __restrict__ bhh0,
    const float* __restrict__ Wih1, const float* __restrict__ Whh1,
    const float* __restrict__ bih1, const float* __restrict__ bhh1,
    const float* __restrict__ Wih2, const float* __restrict__ Whh2,
    const float* __restrict__ bih2, const float* __restrict__ bhh2,
    const float* __restrict__ Wfc, const float* __restrict__ bfc,
    float* __restrict__ out)
{
  __shared__ __align__(16) short hb[3][8][16][72];  // [layer][t&7][batch][j], 55296 B

  const int tid = threadIdx.x;
  const int wv  = __builtin_amdgcn_readfirstlane(tid >> 6);  // 0..2 == layer
  const int ln  = tid & 63;
  const int q   = ln >> 4;        // K=32 k-quad / K=16 row-quad
  const int m15 = ln & 15;
  const int bbase = (int)blockIdx.x * 16;

  // ---------- this wave's layer parameters ----------
  const float* Wih = (wv == 0) ? Wih0 : (wv == 1) ? Wih1 : Wih2;
  const float* Whh = (wv == 0) ? Whh0 : (wv == 1) ? Whh1 : Whh2;
  const float* bi  = (wv == 0) ? bih0 : (wv == 1) ? bih1 : bih2;
  const float* bh  = (wv == 0) ? bhh0 : (wv == 1) ? bhh1 : bhh2;
  const int kin = (wv == 0) ? 32 : 64;

  // ---------- weights (VGPR-resident) ----------
  // input projection at K=32 (upstream arrives as K=32 B-frags from LDS / x);
  // own recurrence at K=16 (register-carried state via D==B identity).
  s16x8 wiA[4], wiB[4];
  s16x4 wh16[4][4];
  const s16x8 z8 = {0, 0, 0, 0, 0, 0, 0, 0};
#pragma unroll
  for (int t4 = 0; t4 < 4; ++t4) {
    const int row = 16 * t4 + m15;
    wiA[t4] = wfragA32(Wih, kin, row, 8 * q);
    wiB[t4] = wv ? wfragA32(Wih, 64, row, 32 + 8 * q) : z8;   // layer 0: K=32 only
#pragma unroll
    for (int kf = 0; kf < 4; ++kf)
      wh16[t4][kf] = wfragA16(Whh, 64, row, 16 * kf + 4 * q);
  }

  // ---------- biases pre-scaled; lane's j = 16*t4 + 4*q + r ----------
  float bsc[4][4];
#pragma unroll
  for (int t4 = 0; t4 < 4; ++t4)
#pragma unroll
    for (int r = 0; r < 4; ++r) {
      const int j = 16 * t4 + 4 * q + r;
      bsc[t4][r] = (bi[j] + bh[j]) * K2LOG2E;
    }

  const fx4 z4 = {0.f, 0.f, 0.f, 0.f};
  const s16x4 z2 = {0, 0, 0, 0};
  s16x4 hf[4] = {z2, z2, z2, z2};   // own state h_wv(t-1), K=16 B-frags (regs)

  // ---------- wave-0 x buffer: 4 t's of this interval ----------
  const float* xr = x + (size_t)(bbase + m15) * (80 * 32) + 8 * q;
  fx4 xb0[4], xb1[4];
  if (wv == 0) {
#pragma unroll
    for (int jj = 0; jj < 4; ++jj) {          // preload t = 0..3
      xb0[jj] = *(const fx4*)(xr + jj * 32);
      xb1[jj] = *(const fx4*)(xr + jj * 32 + 4);
    }
  }

  for (int m = 0; m < 22; ++m) {
    const int lt0 = 4 * (m - wv);             // first t of this interval
    if (0 <= lt0 && lt0 <= 76) {              // wave-uniform
      // ---- interval top: gather all 4 inputs ----
      s16x8 inA[4], inB[4];
      if (wv == 0) {
#pragma unroll
        for (int jj = 0; jj < 4; ++jj) {
          union { unsigned u[4]; s16x8 v; } xp;
          xp.u[0] = pk2bf(xb0[jj][0], xb0[jj][1]);
          xp.u[1] = pk2bf(xb0[jj][2], xb0[jj][3]);
          xp.u[2] = pk2bf(xb1[jj][0], xb1[jj][1]);
          xp.u[3] = pk2bf(xb1[jj][2], xb1[jj][3]);
          inA[jj] = xp.v; inB[jj] = z8;
        }
        // refill for next interval (t = lt0+4 .. lt0+7, clamped); drains at barrier
#pragma unroll
        for (int jj = 0; jj < 4; ++jj) {
          const int tt = (lt0 + 4 + jj <= 79) ? lt0 + 4 + jj : 79;
          xb0[jj] = *(const fx4*)(xr + tt * 32);
          xb1[jj] = *(const fx4*)(xr + tt * 32 + 4);
        }
      } else {
#pragma unroll
        for (int jj = 0; jj < 4; ++jj) {
          const short* up = &hb[wv - 1][(lt0 + jj) & 7][m15][8 * q];
          inA[jj] = *(const s16x8*)(up);
          inB[jj] = *(const s16x8*)(up + 32);
        }
      }
      // ---- 4 sequential steps (own recurrence register-carried) ----
#pragma unroll
      for (int jj = 0; jj < 4; ++jj) {
        const int st = (lt0 + jj) & 7;
        fx4 acc[4];
#pragma unroll
        for (int t4 = 0; t4 < 4; ++t4) acc[t4] = MFMA32(wiA[t4], inA[jj], z4);
        if (wv) {
#pragma unroll
          for (int t4 = 0; t4 < 4; ++t4) acc[t4] = MFMA32(wiB[t4], inB[jj], acc[t4]);
        }
#pragma unroll
        for (int kf = 0; kf < 4; ++kf)
#pragma unroll
          for (int t4 = 0; t4 < 4; ++t4) acc[t4] = MFMA16(wh16[t4][kf], hf[kf], acc[t4]);
        // tanh -> new own state (D==B identity) + LDS publish for downstream
        short* wb = &hb[wv][st][m15][4 * q];
#pragma unroll
        for (int t4 = 0; t4 < 4; ++t4) {
          s16x4 hv = tanh_pack(acc[t4], bsc[t4]);
          hf[t4] = hv;
          *(s16x4*)(wb + 16 * t4) = hv;
        }
      }
    }
    __syncthreads();                          // ONE barrier per 4-step interval
  }

  // ---------- FC head: wave 2's hf == h2(79), K=16 B-frag layout ----------
  if (wv == 2) {
    float sv = 0.f;
#pragma unroll
    for (int kf = 0; kf < 4; ++kf)
#pragma unroll
      for (int i = 0; i < 4; ++i)
        sv += bf2f(hf[kf][i]) * Wfc[16 * kf + 4 * q + i];
    sv += __shfl_xor(sv, 16, 64);
    sv += __shfl_xor(sv, 32, 64);
    if (ln < 16) out[bbase + ln] = sv + bfc[0];
  }
}

extern "C" void kernel_launch(void* const* d_in, const int* in_sizes, int n_in,
                              void* d_out, int out_size, void* d_ws, size_t ws_size,
                              hipStream_t stream) {
  const float* x    = (const float*)d_in[0];
  const float* Wih0 = (const float*)d_in[1];
  const float* Whh0 = (const float*)d_in[2];
  const float* bih0 = (const float*)d_in[3];
  const float* bhh0 = (const float*)d_in[4];
  const float* Wih1 = (const float*)d_in[5];
  const float* Whh1 = (const float*)d_in[6];
  const float* bih1 = (const float*)d_in[7];
  const float* bhh1 = (const float*)d_in[8];
  const float* Wih2 = (const float*)d_in[9];
  const float* Whh2 = (const float*)d_in[10];
  const float* bih2 = (const float*)d_in[11];
  const float* bhh2 = (const float*)d_in[12];
  const float* Wfc  = (const float*)d_in[13];
  const float* bfc  = (const float*)d_in[14];

  // 512 blocks x 192 thr (3 waves = 3 pipelined layers), 16 batch rows per block.
  rnn3_chunk4<<<dim3(512), dim3(192), 0, stream>>>(
      x, Wih0, Whh0, bih0, bhh0, Wih1, Whh1, bih1, bhh1,
      Wih2, Whh2, bih2, bhh2, Wfc, bfc, (float*)d_out);
}